// Round 11
// baseline (1290.827 us; speedup 1.0000x reference)
//
#include <hip/hip_runtime.h>
#include <hip/hip_bf16.h>
#include <hip/hip_fp16.h>

#define Bn  128
#define Ln  256
#define En  300
#define Hn  128
#define Cn  4
#define Dn  256     // 2H
#define G3n 384     // 3H
#define BLn (Bn * Ln)   // 32768

typedef __hip_bfloat16 bf16;
typedef short s16x8 __attribute__((ext_vector_type(8)));
typedef float f32x4 __attribute__((ext_vector_type(4)));
typedef _Float16 h16x2 __attribute__((ext_vector_type(2)));

__device__ __forceinline__ float ldf(const float* p) { return *p; }
__device__ __forceinline__ float ldf(const bf16* p)  { return __bfloat162float(*p); }
__device__ __forceinline__ void stf(float* p, float v) { *p = v; }
__device__ __forceinline__ void stf(bf16* p, float v)  { *p = __float2bfloat16(v); }

__device__ __forceinline__ ushort f2bf(float f) {
    bf16 h = __float2bfloat16(f);
    return *reinterpret_cast<ushort*>(&h);
}
__device__ __forceinline__ float bfu(ushort x) {
    unsigned t = ((unsigned)x) << 16;
    return __builtin_bit_cast(float, t);
}

#if __has_builtin(__builtin_amdgcn_fdot2)
__device__ __forceinline__ float dot2f(h16x2 w, h16x2 h, float c) {
    return __builtin_amdgcn_fdot2(w, h, c, false);
}
#else
__device__ __forceinline__ float dot2f(h16x2 w, h16x2 h, float c) {
    return fmaf((float)w[0], (float)h[0], fmaf((float)w[1], (float)h[1], c));
}
#endif
#define BCH(x) __builtin_bit_cast(h16x2, x)

// uniform lane broadcast on the VALU/SALU pipe (not LDS)
__device__ __forceinline__ float rdl(float v, int l) {
    return __builtin_bit_cast(float,
        __builtin_amdgcn_readlane(__builtin_bit_cast(int, v), l));
}

// 16B-or-8B load of 4 values, fp32 or bf16 source
__device__ __forceinline__ float4 ld4f(const float* p) { return *(const float4*)p; }
__device__ __forceinline__ float4 ld4f(const bf16* p) {
    ushort4 u = *(const ushort4*)p;
    return make_float4(bfu(u.x), bfu(u.y), bfu(u.z), bfu(u.w));
}

// ---------------------------------------------------------------------------
// MFMA bf16 GEMM: C[M,N] = A[M,K] * W^T + bias   (W is (N,K) row-major)
//   AT/WTp in {float,bf16}; GATHER: A row m = A[gidx[m]*K ..]
//   SM==1: store C[(m>>8),n,(m&255)]
// 128x128 tile, 4 waves (2x2 of 64x64), BK=32, LDS rows padded to 40 bf16.
// ---------------------------------------------------------------------------
template<class AT, class WTp, class OT, bool GATHER, int SM>
__global__ __launch_bounds__(256)
void gemm_mfma(const AT* __restrict__ A, const WTp* __restrict__ W,
               const float* __restrict__ bias, OT* __restrict__ Cout,
               const int* __restrict__ gidx, int M, int N, int K)
{
    __shared__ ushort Asm[128 * 40];
    __shared__ ushort Bsm[128 * 40];
    const int bm = blockIdx.y * 128, bn = blockIdx.x * 128;
    const int tid = threadIdx.x;
    const int lane = tid & 63, w = tid >> 6, wr = w >> 1, wc = w & 1;

    const AT* arow[4];
    const WTp* brow[4];
#pragma unroll
    for (int u = 0; u < 4; ++u) {
        const int idx = tid + u * 256;
        const int m = idx >> 3;
        arow[u] = A + (size_t)(GATHER ? gidx[bm + m] : (bm + m)) * K;
        brow[u] = W + (size_t)(bn + m) * K;
    }

    f32x4 acc[4][4] = {};
    const int nkt = (K + 31) >> 5;
    for (int kt = 0; kt < nkt; ++kt) {
        const int k0 = kt << 5;
#pragma unroll
        for (int u = 0; u < 4; ++u) {
            const int idx = tid + u * 256;
            const int m = idx >> 3, kq = idx & 7;
            const int kb = k0 + kq * 4;
            float4 v, q;
            if (kb + 4 <= K) {
                v = ld4f(arow[u] + kb);
                q = ld4f(brow[u] + kb);
            } else {
                v.x = kb + 0 < K ? ldf(&arow[u][kb + 0]) : 0.f;
                v.y = kb + 1 < K ? ldf(&arow[u][kb + 1]) : 0.f;
                v.z = kb + 2 < K ? ldf(&arow[u][kb + 2]) : 0.f;
                v.w = kb + 3 < K ? ldf(&arow[u][kb + 3]) : 0.f;
                q.x = kb + 0 < K ? ldf(&brow[u][kb + 0]) : 0.f;
                q.y = kb + 1 < K ? ldf(&brow[u][kb + 1]) : 0.f;
                q.z = kb + 2 < K ? ldf(&brow[u][kb + 2]) : 0.f;
                q.w = kb + 3 < K ? ldf(&brow[u][kb + 3]) : 0.f;
            }
            *(ushort4*)&Asm[m * 40 + kq * 4] =
                make_ushort4(f2bf(v.x), f2bf(v.y), f2bf(v.z), f2bf(v.w));
            *(ushort4*)&Bsm[m * 40 + kq * 4] =
                make_ushort4(f2bf(q.x), f2bf(q.y), f2bf(q.z), f2bf(q.w));
        }
        __syncthreads();
        s16x8 af[4], bfr[4];
#pragma unroll
        for (int t = 0; t < 4; ++t) {
            af[t]  = *(const s16x8*)&Asm[(wr * 64 + t * 16 + (lane & 15)) * 40 + (lane >> 4) * 8];
            bfr[t] = *(const s16x8*)&Bsm[(wc * 64 + t * 16 + (lane & 15)) * 40 + (lane >> 4) * 8];
        }
#pragma unroll
        for (int mf = 0; mf < 4; ++mf)
#pragma unroll
            for (int nf = 0; nf < 4; ++nf)
                acc[mf][nf] = __builtin_amdgcn_mfma_f32_16x16x32_bf16(
                    af[mf], bfr[nf], acc[mf][nf], 0, 0, 0);
        __syncthreads();
    }

#pragma unroll
    for (int mf = 0; mf < 4; ++mf)
#pragma unroll
        for (int nf = 0; nf < 4; ++nf) {
            const int col = bn + wc * 64 + nf * 16 + (lane & 15);
            const float bv_ = bias ? bias[col] : 0.f;
#pragma unroll
            for (int i = 0; i < 4; ++i) {
                const int row = bm + wr * 64 + mf * 16 + (lane >> 4) * 4 + i;
                const float v = acc[mf][nf][i] + bv_;
                if (SM == 1)
                    stf(&Cout[((size_t)(row >> 8) * N + col) * 256 + (row & 255)], v);
                else
                    stf(&Cout[(size_t)row * N + col], v);
            }
        }
}

// ---------------------------------------------------------------------------
// GRU scan v8: LDS b128 weights + readlane h-distribution.
// r10 model closure: 32 LDS instr/thread/step x 6 waves x ~12cyc = the
// measured 2690 cyc/step. This version: 16 weight b128 + ONE h b128 (lane
// owns chunk lane&15; wave holds h 4x-replicated) + readlane broadcasts on
// the VALU pipe (VALUBusy was only 23%). LDS 32->17 instr/thread/step.
// ---------------------------------------------------------------------------
__global__ __launch_bounds__(384, 1)
void gru_scan_v8(const bf16* __restrict__ gx, const float* __restrict__ w_hh,
                 const float* __restrict__ b_hh, bf16* __restrict__ out)
{
    const int b = blockIdx.x, dir = blockIdx.y;
    const int r = threadIdx.x;               // gate row 0..383
    const int lane = r & 63;
    __shared__ __align__(16) ushort wl[384 * 136];   // 272B rows, 104448 B
    __shared__ __align__(16) ushort hp16[128];       // h as f16
    __shared__ float h_sh[128];
    __shared__ float rs[128], zs[128], gxn[128], ghn[128];

    // stage weights once (coalesced)
    const float* wbase = w_hh + (size_t)dir * G3n * Hn;
    for (int idx = r; idx < G3n * 64; idx += 384) {
        const int row = idx >> 6, k2 = idx & 63;
        const float2 v = *(const float2*)(wbase + row * Hn + 2 * k2);
        h16x2 p; p[0] = (_Float16)v.x; p[1] = (_Float16)v.y;
        *(h16x2*)&wl[row * 136 + 2 * k2] = p;
    }
    if (r < 128) { hp16[r] = 0; h_sh[r] = 0.f; }
    const float bh = b_hh[dir * G3n + r];
    __syncthreads();

    const size_t g0 = (size_t)b * Ln * 768 + dir * G3n + r
                      + (dir ? (size_t)(Ln - 1) * 768 : 0);
    const long gstep = dir ? -768L : 768L;
    float gcur = ldf(&gx[g0]);
    float gnx  = ldf(&gx[g0 + gstep]);

    const ushort* wrow = &wl[r * 136];

    for (int s = 0; s < Ln; ++s) {
        const int t = dir ? (Ln - 1 - s) : s;
        float gn2 = 0.f;
        if (s + 2 < Ln) gn2 = ldf(&gx[g0 + (long)(s + 2) * gstep]);

        // lane's own h chunk: 16B = 8 f16 = k in [8*(lane&15), +8)
        const float4 hown = *(const float4*)&hp16[(lane & 15) * 8];

        float a0 = 0.f, a1 = 0.f, a2 = 0.f, a3 = 0.f;
#pragma unroll
        for (int j = 0; j < 16; ++j) {
            const float4 wv = *(const float4*)&wrow[8 * j];   // k [8j, 8j+8)
            a0 = dot2f(BCH(wv.x), BCH(rdl(hown.x, j)), a0);
            a1 = dot2f(BCH(wv.y), BCH(rdl(hown.y, j)), a1);
            a2 = dot2f(BCH(wv.z), BCH(rdl(hown.z, j)), a2);
            a3 = dot2f(BCH(wv.w), BCH(rdl(hown.w, j)), a3);
        }
        const float acc = (a0 + a1) + (a2 + a3) + bh;

        if (r < 128)      rs[r]       = 1.f / (1.f + expf(-(gcur + acc)));
        else if (r < 256) zs[r - 128] = 1.f / (1.f + expf(-(gcur + acc)));
        else { gxn[r - 256] = gcur; ghn[r - 256] = acc; }
        __syncthreads();

        if (r < 128) {
            const int j = r;
            const float nn = tanhf(gxn[j] + rs[j] * ghn[j]);
            const float hnew = (1.f - zs[j]) * nn + zs[j] * h_sh[j];
            h_sh[j] = hnew;
            const _Float16 hf = (_Float16)hnew;
            hp16[j] = __builtin_bit_cast(ushort, hf);
            out[((size_t)b * Ln + t) * Dn + dir * Hn + j] = __float2bfloat16(hnew);
        }
        __syncthreads();
        gcur = gnx; gnx = gn2;
    }
}

// ---------------------------------------------------------------------------
// attn score, MFMA, bf16 inputs: s[b,i] = sum_j tanh(x_b[i]·mat_b[j] + bc)
// ---------------------------------------------------------------------------
__global__ __launch_bounds__(256)
void attn_score_mfma(const bf16* __restrict__ x, const bf16* __restrict__ matc,
                     const float* __restrict__ attb, int c, float* __restrict__ sout)
{
    const int it = blockIdx.x, b = blockIdx.y;
    const bf16* A  = x    + ((size_t)b * 256 + it * 128) * 256;
    const bf16* Bm = matc + (size_t)b * 65536;
    __shared__ ushort Xs[128 * 40];
    __shared__ ushort Ms[128 * 40];
    const int tid = threadIdx.x, lane = tid & 63, w = tid >> 6;
    const float bc = attb[c];
    float psum[2][4] = {};

    for (int jt = 0; jt < 2; ++jt) {
        f32x4 acc[2][8] = {};
        for (int kt = 0; kt < 8; ++kt) {
            const int k0 = kt << 5;
#pragma unroll
            for (int u = 0; u < 2; ++u) {     // straight 16B copies (bf16 src)
                const int idx = tid + u * 256;
                const int m = idx >> 2, q = idx & 3;
                *(s16x8*)&Xs[m * 40 + q * 8] =
                    *(const s16x8*)&A[(size_t)m * 256 + k0 + q * 8];
                *(s16x8*)&Ms[m * 40 + q * 8] =
                    *(const s16x8*)&Bm[(size_t)(jt * 128 + m) * 256 + k0 + q * 8];
            }
            __syncthreads();
            s16x8 af[2], bfr[8];
#pragma unroll
            for (int t = 0; t < 2; ++t)
                af[t] = *(const s16x8*)&Xs[(w * 32 + t * 16 + (lane & 15)) * 40 + (lane >> 4) * 8];
#pragma unroll
            for (int t = 0; t < 8; ++t)
                bfr[t] = *(const s16x8*)&Ms[(t * 16 + (lane & 15)) * 40 + (lane >> 4) * 8];
#pragma unroll
            for (int mf = 0; mf < 2; ++mf)
#pragma unroll
                for (int nf = 0; nf < 8; ++nf)
                    acc[mf][nf] = __builtin_amdgcn_mfma_f32_16x16x32_bf16(
                        af[mf], bfr[nf], acc[mf][nf], 0, 0, 0);
            __syncthreads();
        }
#pragma unroll
        for (int mf = 0; mf < 2; ++mf)
#pragma unroll
            for (int nf = 0; nf < 8; ++nf)
#pragma unroll
                for (int i = 0; i < 4; ++i)
                    psum[mf][i] += tanhf(acc[mf][nf][i] + bc);
    }

#pragma unroll
    for (int mf = 0; mf < 2; ++mf)
#pragma unroll
        for (int i = 0; i < 4; ++i) {
            float v = psum[mf][i];
            v += __shfl_xor(v, 1); v += __shfl_xor(v, 2);
            v += __shfl_xor(v, 4); v += __shfl_xor(v, 8);
            if ((lane & 15) == 0)
                sout[b * 256 + it * 128 + w * 32 + mf * 16 + (lane >> 4) * 4 + i] = v;
        }
}

// al[row] = sum_e sigmoid(gv[row,e] + bv[e]) * wv1[e]   (one wave per row)
__global__ __launch_bounds__(256)
void gv_reduce(const bf16* __restrict__ gv, const float* __restrict__ bv,
               const float* __restrict__ wv1, float* __restrict__ al)
{
    const int row = blockIdx.x * 4 + (threadIdx.x >> 6);
    const int l = threadIdx.x & 63;
    const ushort4 u = *(const ushort4*)&gv[(size_t)row * 256 + l * 4];
    const float4 bb = *(const float4*)(bv + l * 4);
    const float4 w  = *(const float4*)(wv1 + l * 4);
    float s = w.x / (1.f + expf(-(bfu(u.x) + bb.x)))
            + w.y / (1.f + expf(-(bfu(u.y) + bb.y)))
            + w.z / (1.f + expf(-(bfu(u.z) + bb.z)))
            + w.w / (1.f + expf(-(bfu(u.w) + bb.w)));
#pragma unroll
    for (int m = 1; m < 64; m <<= 1) s += __shfl_xor(s, m);
    if (l == 0) al[row] = s;
}

// transpose 4 matrices of 256x256 (src[c][d][e] fp32 -> dst[c][e][d] bf16)
__global__ void transpose256(const float* __restrict__ src, bf16* __restrict__ dst)
{
    const float* s = src + (size_t)blockIdx.x * 65536;
    bf16* d = dst + (size_t)blockIdx.x * 65536;
    __shared__ float t[32][33];
    const int tx = threadIdx.x & 31, ty8 = threadIdx.x >> 5;
    for (int bi = 0; bi < 8; ++bi)
        for (int bj = 0; bj < 8; ++bj) {
            __syncthreads();
            for (int r = ty8; r < 32; r += 8)
                t[r][tx] = s[(size_t)(bi * 32 + r) * 256 + bj * 32 + tx];
            __syncthreads();
            for (int r = ty8; r < 32; r += 8)
                stf(&d[(size_t)(bj * 32 + r) * 256 + bi * 32 + tx], t[tx][r]);
        }
}

__global__ void softmax256(const float* __restrict__ in, float* __restrict__ out)
{
    __shared__ float red[256];
    const int row = blockIdx.x, t = threadIdx.x;
    const float v = in[(size_t)row * 256 + t];
    red[t] = v; __syncthreads();
    for (int off = 128; off; off >>= 1) {
        if (t < off) red[t] = fmaxf(red[t], red[t + off]);
        __syncthreads();
    }
    const float mx = red[0]; __syncthreads();
    const float e = expf(v - mx);
    red[t] = e; __syncthreads();
    for (int off = 128; off; off >>= 1) {
        if (t < off) red[t] += red[t + off];
        __syncthreads();
    }
    out[(size_t)row * 256 + t] = e / red[0];
}

// new[c,b,d] = sum_l aa[c,b,l] * x[b,l,d]   (x bf16)
__global__ void weighted_sum_kernel(const float* __restrict__ aa,
                                    const bf16* __restrict__ x,
                                    float* __restrict__ outnew)
{
    const int b = blockIdx.x, c = blockIdx.y, d = threadIdx.x;
    __shared__ float w[Ln];
    w[d] = aa[((size_t)c * Bn + b) * Ln + d];
    __syncthreads();
    float acc = 0.f;
    for (int l = 0; l < Ln; ++l)
        acc += w[l] * ldf(&x[((size_t)b * Ln + l) * Dn + d]);
    outnew[((size_t)c * Bn + b) * Dn + d] = acc;
}

// pack conv filter rows (216) into 256x256 fp32 (rows 216+ zero)
__global__ void wpack_fill(const float* __restrict__ w0, const float* __restrict__ w1,
                           const float* __restrict__ w2, const float* __restrict__ w3,
                           float* __restrict__ wp)
{
    const int f = blockIdx.x;
    if (f < 4) {
        const int cnt[4]  = {4096, 9216, 16384, 25600};
        const int boff[4] = {0, 4096, 13312, 29696};
        const float* src = f == 0 ? w0 : f == 1 ? w1 : f == 2 ? w2 : w3;
        for (int i = threadIdx.x; i < cnt[f]; i += blockDim.x)
            wp[boff[f] + i] = src[i];
    } else {
        for (int i = threadIdx.x; i < 65536 - 55296; i += blockDim.x)
            wp[55296 + i] = 0.f;
    }
}

// nwd[b,row] = dot(new[c_of_row, b, :], wpack[row, :])
__global__ __launch_bounds__(256)
void nwd_kernel(const float* __restrict__ nw, const float* __restrict__ wp,
                float* __restrict__ nwd)
{
    const int b = blockIdx.x;
    __shared__ float ns[4][256];
    for (int i = threadIdx.x; i < 1024; i += 256)
        ns[i >> 8][i & 255] = nw[((size_t)((i >> 8) * Bn + b) << 8) + (i & 255)];
    __syncthreads();
    const int row = threadIdx.x;
    if (row < 216) {
        int f, base;
        if (row < 16)       { f = 0; base = 0; }
        else if (row < 52)  { f = 1; base = 16; }
        else if (row < 116) { f = 2; base = 52; }
        else                { f = 3; base = 116; }
        const int fs = f + 2, local = row - base;
        const int c = (local / fs) & 3;
        const float* wr = wp + (size_t)row * 256;
        float acc = 0.f;
        for (int k = 0; k < 256; ++k) acc += ns[c][k] * wr[k];
        nwd[b * 256 + row] = acc;
    }
}

// conv+relu+maxpool via decomposition over a-weighted x rows + new offset
__global__ __launch_bounds__(256)
void conv_combine(const float* __restrict__ xwT, const float* __restrict__ a,
                  const float* __restrict__ nwd, const float* __restrict__ cb,
                  float* __restrict__ pool, int fs, int base, int poff)
{
    const int b = blockIdx.x, tid = threadIdx.x;
    __shared__ float ash[4][256];
    __shared__ float basev[5];
    __shared__ float red[256];
    for (int i = tid; i < 1024; i += 256)
        ash[i >> 8][i & 255] = a[((size_t)((i >> 8) * Bn + b) << 8) + (i & 255)];
    if (tid < fs) {
        float s = cb[tid];
        for (int c = 0; c < 4; ++c)
            for (int kh = 0; kh < fs; ++kh)
                s += nwd[b * 256 + base + (tid * 4 + c) * fs + kh];
        basev[tid] = s;
    }
    __syncthreads();
    const int ni = Ln - fs + 1;
    const float* xb = xwT + ((size_t)b << 16);
    for (int o = 0; o < fs; ++o) {
        float best = 0.f;
        if (tid < ni) {
            float acc = basev[o];
            for (int c = 0; c < 4; ++c)
                for (int kh = 0; kh < fs; ++kh) {
                    const int row = base + (o * 4 + c) * fs + kh;
                    acc += ash[c][tid + kh] * xb[(row << 8) + tid + kh];
                }
            best = fmaxf(acc, 0.f);
        }
        red[tid] = best; __syncthreads();
        for (int off = 128; off; off >>= 1) {
            if (tid < off) red[tid] = fmaxf(red[tid], red[tid + off]);
            __syncthreads();
        }
        if (tid == 0) pool[b * 14 + poff + o] = red[0];
        __syncthreads();
    }
}

__global__ void fc_kernel(const float* __restrict__ pool, const float* __restrict__ fw,
                          const float* __restrict__ fb, float* __restrict__ out)
{
    const int i = threadIdx.x;           // 256 = B*OUT
    const int b = i >> 1, o = i & 1;
    float acc = fb[o];
#pragma unroll
    for (int f = 0; f < 14; ++f) acc += pool[b * 14 + f] * fw[o * 14 + f];
    out[i] = acc;
}

// ---------------------------------------------------------------------------
extern "C" void kernel_launch(void* const* d_in, const int* in_sizes, int n_in,
                              void* d_out, int out_size, void* d_ws, size_t ws_size,
                              hipStream_t stream)
{
    const int*   utt    = (const int*)  d_in[0];
    const float* emb    = (const float*)d_in[2];
    const float* w_ih0  = (const float*)d_in[3];
    const float* w_hh0  = (const float*)d_in[4];
    const float* b_ih0  = (const float*)d_in[5];
    const float* b_hh0  = (const float*)d_in[6];
    const float* w_ih1  = (const float*)d_in[7];
    const float* w_hh1  = (const float*)d_in[8];
    const float* b_ih1  = (const float*)d_in[9];
    const float* b_hh1  = (const float*)d_in[10];
    const float* att_w  = (const float*)d_in[11];
    const float* att_b  = (const float*)d_in[12];
    const float* att_wv2= (const float*)d_in[13];
    const float* att_bv = (const float*)d_in[14];
    const float* att_wv1= (const float*)d_in[15];
    const float* fc_w   = (const float*)d_in[16];
    const float* fc_b   = (const float*)d_in[17];
    const float* cw[4] = {(const float*)d_in[18], (const float*)d_in[20],
                          (const float*)d_in[22], (const float*)d_in[24]};
    const float* cb[4] = {(const float*)d_in[19], (const float*)d_in[21],
                          (const float*)d_in[23], (const float*)d_in[25]};

    float* ws = (float*)d_ws;
    // bf16 dataflow: H1/H2/MATc/GV/WT stored bf16 (all GEMMs already
    // quantized these to bf16 in staging -- storage-level bf16 is free
    // accuracy-wise and halves the traffic). extent ~88 MB (121 proven safe).
    bf16*  GX   = (bf16*)ws;                          // 12,582,912 f32 slots
    bf16*  H1   = (bf16*)(ws + 12582912);             //  4,194,304 slots
    bf16*  H2   = (bf16*)(ws + 12582912 + 4194304);   //  4,194,304 slots
    bf16*  WT   = (bf16*)(ws + 20971520);             //    131,072 slots
    float* WP   = ws + 20971520 + 131072;             //     65,536 f
    float* S    = WP + 65536;                         //    131,072 f
    float* Aa   = S + 131072;
    float* AL   = Aa + 131072;
    float* AAa  = AL + 131072;
    float* NEW_ = AAa + 131072;
    float* NWD  = NEW_ + 131072;                      //     32,768 f
    float* POOL = NWD + 32768;                        //      1,792 f
    bf16*  MATc = H1;                  // alias (H1 dead after layer-1 gemm)
    bf16*  GV   = (bf16*)ws;           // alias gx region (dead after scan 2)
    float* XWT  = ws;                  // alias (GV dead after gv_reduce)

    // layer 0 + scan
    gemm_mfma<float, float, bf16, true, 0><<<dim3(6, 256), 256, 0, stream>>>(
        emb, w_ih0, b_ih0, GX, utt, BLn, 768, En);
    gru_scan_v8<<<dim3(Bn, 2), 384, 0, stream>>>(GX, w_hh0, b_hh0, H1);
    // layer 1 + scan
    gemm_mfma<bf16, float, bf16, false, 0><<<dim3(6, 256), 256, 0, stream>>>(
        H1, w_ih1, b_ih1, GX, nullptr, BLn, 768, Dn);
    gru_scan_v8<<<dim3(Bn, 2), 384, 0, stream>>>(GX, w_hh1, b_hh1, H2);

    // scalar attention: mat_c = x @ att_w[c], fused tanh-sum scores
    transpose256<<<4, 256, 0, stream>>>(att_w, WT);
    for (int c = 0; c < 4; ++c) {
        gemm_mfma<bf16, bf16, bf16, false, 0><<<dim3(2, 256), 256, 0, stream>>>(
            H2, WT + (size_t)c * 65536, nullptr, MATc, nullptr, BLn, Dn, Dn);
        attn_score_mfma<<<dim3(2, Bn), 256, 0, stream>>>(
            H2, MATc, att_b, c, S + (size_t)c * 32768);
    }
    softmax256<<<Cn * Bn, 256, 0, stream>>>(S, Aa);

    // vector attention: gv = x @ wv2[c], reduce with sigmoid*wv1
    transpose256<<<4, 256, 0, stream>>>(att_wv2, WT);
    for (int c = 0; c < 4; ++c) {
        gemm_mfma<bf16, bf16, bf16, false, 0><<<dim3(2, 256), 256, 0, stream>>>(
            H2, WT + (size_t)c * 65536, nullptr, GV, nullptr, BLn, Dn, Dn);
        gv_reduce<<<BLn / 4, 256, 0, stream>>>(
            GV, att_bv + c * Dn, att_wv1 + c * Dn, AL + (size_t)c * BLn);
    }
    softmax256<<<Cn * Bn, 256, 0, stream>>>(AL, AAa);
    weighted_sum_kernel<<<dim3(Bn, Cn), 256, 0, stream>>>(AAa, H2, NEW_);

    // conv stage via xw GEMM decomposition (Cf never materialized)
    wpack_fill<<<5, 256, 0, stream>>>(cw[0], cw[1], cw[2], cw[3], WP);
    gemm_mfma<bf16, float, float, false, 1><<<dim3(2, 256), 256, 0, stream>>>(
        H2, WP, nullptr, XWT, nullptr, BLn, Dn, Dn);
    nwd_kernel<<<Bn, 256, 0, stream>>>(NEW_, WP, NWD);

    const int baserow[4] = {0, 16, 52, 116};
    const int poff[4]    = {0, 2, 5, 9};
    for (int f = 0; f < 4; ++f)
        conv_combine<<<Bn, 256, 0, stream>>>(XWT, Aa, NWD, cb[f], POOL, f + 2, baserow[f], poff[f]);

    fc_kernel<<<1, 256, 0, stream>>>(POOL, fc_w, fc_b, (float*)d_out);
}

// Round 12
// 1126.585 us; speedup vs baseline: 1.1458x; 1.1458x over previous
//
#include <hip/hip_runtime.h>
#include <hip/hip_bf16.h>
#include <hip/hip_fp16.h>

#define Bn  128
#define Ln  256
#define En  300
#define Hn  128
#define Cn  4
#define Dn  256     // 2H
#define G3n 384     // 3H
#define BLn (Bn * Ln)   // 32768

typedef __hip_bfloat16 bf16;
typedef short s16x8 __attribute__((ext_vector_type(8)));
typedef float f32x4 __attribute__((ext_vector_type(4)));
typedef _Float16 h16x2 __attribute__((ext_vector_type(2)));

__device__ __forceinline__ float ldf(const float* p) { return *p; }
__device__ __forceinline__ float ldf(const bf16* p)  { return __bfloat162float(*p); }
__device__ __forceinline__ void stf(float* p, float v) { *p = v; }
__device__ __forceinline__ void stf(bf16* p, float v)  { *p = __float2bfloat16(v); }

__device__ __forceinline__ ushort f2bf(float f) {
    bf16 h = __float2bfloat16(f);
    return *reinterpret_cast<ushort*>(&h);
}
__device__ __forceinline__ float bfu(ushort x) {
    unsigned t = ((unsigned)x) << 16;
    return __builtin_bit_cast(float, t);
}

#if __has_builtin(__builtin_amdgcn_fdot2)
__device__ __forceinline__ float dot2f(h16x2 w, h16x2 h, float c) {
    return __builtin_amdgcn_fdot2(w, h, c, false);
}
#else
__device__ __forceinline__ float dot2f(h16x2 w, h16x2 h, float c) {
    return fmaf((float)w[0], (float)h[0], fmaf((float)w[1], (float)h[1], c));
}
#endif
#define BCH(x) __builtin_bit_cast(h16x2, x)

// 16B-or-8B load of 4 values, fp32 or bf16 source
__device__ __forceinline__ float4 ld4f(const float* p) { return *(const float4*)p; }
__device__ __forceinline__ float4 ld4f(const bf16* p) {
    ushort4 u = *(const ushort4*)p;
    return make_float4(bfu(u.x), bfu(u.y), bfu(u.z), bfu(u.w));
}

// ---------------------------------------------------------------------------
// MFMA bf16 GEMM: C[M,N] = A[M,K] * W^T + bias   (W is (N,K) row-major)
//   AT/WTp in {float,bf16}; GATHER: A row m = A[gidx[m]*K ..]
//   SM==1: store C[(m>>8),n,(m&255)]
// ---------------------------------------------------------------------------
template<class AT, class WTp, class OT, bool GATHER, int SM>
__global__ __launch_bounds__(256)
void gemm_mfma(const AT* __restrict__ A, const WTp* __restrict__ W,
               const float* __restrict__ bias, OT* __restrict__ Cout,
               const int* __restrict__ gidx, int M, int N, int K)
{
    __shared__ ushort Asm[128 * 40];
    __shared__ ushort Bsm[128 * 40];
    const int bm = blockIdx.y * 128, bn = blockIdx.x * 128;
    const int tid = threadIdx.x;
    const int lane = tid & 63, w = tid >> 6, wr = w >> 1, wc = w & 1;

    const AT* arow[4];
    const WTp* brow[4];
#pragma unroll
    for (int u = 0; u < 4; ++u) {
        const int idx = tid + u * 256;
        const int m = idx >> 3;
        arow[u] = A + (size_t)(GATHER ? gidx[bm + m] : (bm + m)) * K;
        brow[u] = W + (size_t)(bn + m) * K;
    }

    f32x4 acc[4][4] = {};
    const int nkt = (K + 31) >> 5;
    for (int kt = 0; kt < nkt; ++kt) {
        const int k0 = kt << 5;
#pragma unroll
        for (int u = 0; u < 4; ++u) {
            const int idx = tid + u * 256;
            const int m = idx >> 3, kq = idx & 7;
            const int kb = k0 + kq * 4;
            float4 v, q;
            if (kb + 4 <= K) {
                v = ld4f(arow[u] + kb);
                q = ld4f(brow[u] + kb);
            } else {
                v.x = kb + 0 < K ? ldf(&arow[u][kb + 0]) : 0.f;
                v.y = kb + 1 < K ? ldf(&arow[u][kb + 1]) : 0.f;
                v.z = kb + 2 < K ? ldf(&arow[u][kb + 2]) : 0.f;
                v.w = kb + 3 < K ? ldf(&arow[u][kb + 3]) : 0.f;
                q.x = kb + 0 < K ? ldf(&brow[u][kb + 0]) : 0.f;
                q.y = kb + 1 < K ? ldf(&brow[u][kb + 1]) : 0.f;
                q.z = kb + 2 < K ? ldf(&brow[u][kb + 2]) : 0.f;
                q.w = kb + 3 < K ? ldf(&brow[u][kb + 3]) : 0.f;
            }
            *(ushort4*)&Asm[m * 40 + kq * 4] =
                make_ushort4(f2bf(v.x), f2bf(v.y), f2bf(v.z), f2bf(v.w));
            *(ushort4*)&Bsm[m * 40 + kq * 4] =
                make_ushort4(f2bf(q.x), f2bf(q.y), f2bf(q.z), f2bf(q.w));
        }
        __syncthreads();
        s16x8 af[4], bfr[4];
#pragma unroll
        for (int t = 0; t < 4; ++t) {
            af[t]  = *(const s16x8*)&Asm[(wr * 64 + t * 16 + (lane & 15)) * 40 + (lane >> 4) * 8];
            bfr[t] = *(const s16x8*)&Bsm[(wc * 64 + t * 16 + (lane & 15)) * 40 + (lane >> 4) * 8];
        }
#pragma unroll
        for (int mf = 0; mf < 4; ++mf)
#pragma unroll
            for (int nf = 0; nf < 4; ++nf)
                acc[mf][nf] = __builtin_amdgcn_mfma_f32_16x16x32_bf16(
                    af[mf], bfr[nf], acc[mf][nf], 0, 0, 0);
        __syncthreads();
    }

#pragma unroll
    for (int mf = 0; mf < 4; ++mf)
#pragma unroll
        for (int nf = 0; nf < 4; ++nf) {
            const int col = bn + wc * 64 + nf * 16 + (lane & 15);
            const float bv_ = bias ? bias[col] : 0.f;
#pragma unroll
            for (int i = 0; i < 4; ++i) {
                const int row = bm + wr * 64 + mf * 16 + (lane >> 4) * 4 + i;
                const float v = acc[mf][nf][i] + bv_;
                if (SM == 1)
                    stf(&Cout[((size_t)(row >> 8) * N + col) * 256 + (row & 255)], v);
                else
                    stf(&Cout[(size_t)row * N + col], v);
            }
        }
}

// ---------------------------------------------------------------------------
// GRU scan v9: k-split over 768 threads (12 waves = 3/SIMD).
// r10 (384 thr) was latency-bound: 2690 cyc/step vs ~1550 LDS-BW floor at
// 1.5 waves/SIMD. Thread (row, half) does 8 weight-b128 + 8 h-broadcast-b128
// + 32 dot2; same per-CU LDS instruction count, 2x the TLP. Halves combined
// via part[] LDS (different waves -> no shfl); 3 barriers/step.
// ---------------------------------------------------------------------------
__global__ __launch_bounds__(768, 1)
void gru_scan_v9(const bf16* __restrict__ gx, const float* __restrict__ w_hh,
                 const float* __restrict__ b_hh, bf16* __restrict__ out)
{
    const int b = blockIdx.x, dir = blockIdx.y;
    const int t = threadIdx.x;
    const int half = t >= 384 ? 1 : 0;
    const int r = t - 384 * half;            // gate row 0..383
    __shared__ __align__(16) ushort wl[384 * 136];   // 272B rows, 104448 B
    __shared__ __align__(16) ushort hp16[128];       // h as f16
    __shared__ float h_sh[128];
    __shared__ float part[384];
    __shared__ float rs[128], zs[128], gxn[128], ghn[128];

    // stage weights once (coalesced 8B loads)
    const float* wbase = w_hh + (size_t)dir * G3n * Hn;
    for (int idx = t; idx < G3n * 64; idx += 768) {
        const int row = idx >> 6, k2 = idx & 63;
        const float2 v = *(const float2*)(wbase + row * Hn + 2 * k2);
        h16x2 p; p[0] = (_Float16)v.x; p[1] = (_Float16)v.y;
        *(h16x2*)&wl[row * 136 + 2 * k2] = p;
    }
    if (t < 128) { hp16[t] = 0; h_sh[t] = 0.f; }
    const float bh = b_hh[dir * G3n + r];
    __syncthreads();

    const size_t g0 = (size_t)b * Ln * 768 + dir * G3n + r
                      + (dir ? (size_t)(Ln - 1) * 768 : 0);
    const long gstep = dir ? -768L : 768L;
    float gcur = 0.f, gnx = 0.f;
    if (!half) { gcur = ldf(&gx[g0]); gnx = ldf(&gx[g0 + gstep]); }

    const ushort* wrow  = &wl[r * 136 + half * 64];  // this half's 64 weights
    const ushort* hbase = &hp16[half * 64];          // this half's 64 h vals

    for (int s = 0; s < Ln; ++s) {
        const int tt = dir ? (Ln - 1 - s) : s;
        float gn2 = 0.f;
        if (!half && s + 2 < Ln) gn2 = ldf(&gx[g0 + (long)(s + 2) * gstep]);

        float a0 = 0.f, a1 = 0.f, a2 = 0.f, a3 = 0.f;
#pragma unroll
        for (int j = 0; j < 8; ++j) {
            const float4 wv = *(const float4*)&wrow[8 * j];    // spread read
            const float4 hv = *(const float4*)&hbase[8 * j];   // broadcast
            a0 = dot2f(BCH(wv.x), BCH(hv.x), a0);
            a1 = dot2f(BCH(wv.y), BCH(hv.y), a1);
            a2 = dot2f(BCH(wv.z), BCH(hv.z), a2);
            a3 = dot2f(BCH(wv.w), BCH(hv.w), a3);
        }
        const float acc = (a0 + a1) + (a2 + a3);
        if (half) part[r] = acc;
        __syncthreads();

        if (!half) {
            const float tot = acc + part[r] + bh;
            if (r < 128)      rs[r]       = 1.f / (1.f + expf(-(gcur + tot)));
            else if (r < 256) zs[r - 128] = 1.f / (1.f + expf(-(gcur + tot)));
            else { gxn[r - 256] = gcur; ghn[r - 256] = tot; }
        }
        __syncthreads();

        if (t < 128) {
            const int j = t;
            const float nn = tanhf(gxn[j] + rs[j] * ghn[j]);
            const float hnew = (1.f - zs[j]) * nn + zs[j] * h_sh[j];
            h_sh[j] = hnew;
            const _Float16 hf = (_Float16)hnew;
            hp16[j] = __builtin_bit_cast(ushort, hf);
            out[((size_t)b * Ln + tt) * Dn + dir * Hn + j] = __float2bfloat16(hnew);
        }
        __syncthreads();
        if (!half) { gcur = gnx; gnx = gn2; }
    }
}

// ---------------------------------------------------------------------------
// attn score, MFMA, fused channels: grid (2, B, C); mat has row stride 1024
// (all 4 channels in one buffer, col offset c*256).
// ---------------------------------------------------------------------------
__global__ __launch_bounds__(256)
void attn_score_mfma(const bf16* __restrict__ x, const bf16* __restrict__ matb,
                     const float* __restrict__ attb, float* __restrict__ sout)
{
    const int it = blockIdx.x, b = blockIdx.y, c = blockIdx.z;
    const bf16* A  = x + ((size_t)b * 256 + it * 128) * 256;
    const bf16* Bm = matb + (size_t)b * 256 * 1024 + c * 256;
    __shared__ ushort Xs[128 * 40];
    __shared__ ushort Ms[128 * 40];
    const int tid = threadIdx.x, lane = tid & 63, w = tid >> 6;
    const float bc = attb[c];
    float psum[2][4] = {};

    for (int jt = 0; jt < 2; ++jt) {
        f32x4 acc[2][8] = {};
        for (int kt = 0; kt < 8; ++kt) {
            const int k0 = kt << 5;
#pragma unroll
            for (int u = 0; u < 2; ++u) {     // straight 16B copies (bf16 src)
                const int idx = tid + u * 256;
                const int m = idx >> 2, q = idx & 3;
                *(s16x8*)&Xs[m * 40 + q * 8] =
                    *(const s16x8*)&A[(size_t)m * 256 + k0 + q * 8];
                *(s16x8*)&Ms[m * 40 + q * 8] =
                    *(const s16x8*)&Bm[(size_t)(jt * 128 + m) * 1024 + k0 + q * 8];
            }
            __syncthreads();
            s16x8 af[2], bfr[8];
#pragma unroll
            for (int t = 0; t < 2; ++t)
                af[t] = *(const s16x8*)&Xs[(w * 32 + t * 16 + (lane & 15)) * 40 + (lane >> 4) * 8];
#pragma unroll
            for (int t = 0; t < 8; ++t)
                bfr[t] = *(const s16x8*)&Ms[(t * 16 + (lane & 15)) * 40 + (lane >> 4) * 8];
#pragma unroll
            for (int mf = 0; mf < 2; ++mf)
#pragma unroll
                for (int nf = 0; nf < 8; ++nf)
                    acc[mf][nf] = __builtin_amdgcn_mfma_f32_16x16x32_bf16(
                        af[mf], bfr[nf], acc[mf][nf], 0, 0, 0);
            __syncthreads();
        }
#pragma unroll
        for (int mf = 0; mf < 2; ++mf)
#pragma unroll
            for (int nf = 0; nf < 8; ++nf)
#pragma unroll
                for (int i = 0; i < 4; ++i)
                    psum[mf][i] += tanhf(acc[mf][nf][i] + bc);
    }

#pragma unroll
    for (int mf = 0; mf < 2; ++mf)
#pragma unroll
        for (int i = 0; i < 4; ++i) {
            float v = psum[mf][i];
            v += __shfl_xor(v, 1); v += __shfl_xor(v, 2);
            v += __shfl_xor(v, 4); v += __shfl_xor(v, 8);
            if ((lane & 15) == 0)
                sout[(size_t)c * BLn + b * 256 + it * 128 + w * 32 + mf * 16 + (lane >> 4) * 4 + i] = v;
        }
}

// al[c,row] = sum_e sigmoid(gv[row, c*256+e] + bv[c,e]) * wv1[c,e]
// gv row stride 1024 (fused channels); grid (BLn/4, C)
__global__ __launch_bounds__(256)
void gv_reduce(const bf16* __restrict__ gv, const float* __restrict__ bv,
               const float* __restrict__ wv1, float* __restrict__ al)
{
    const int row = blockIdx.x * 4 + (threadIdx.x >> 6);
    const int c = blockIdx.y;
    const int l = threadIdx.x & 63;
    const ushort4 u = *(const ushort4*)&gv[(size_t)row * 1024 + c * 256 + l * 4];
    const float4 bb = *(const float4*)(bv + c * Dn + l * 4);
    const float4 w  = *(const float4*)(wv1 + c * Dn + l * 4);
    float s = w.x / (1.f + expf(-(bfu(u.x) + bb.x)))
            + w.y / (1.f + expf(-(bfu(u.y) + bb.y)))
            + w.z / (1.f + expf(-(bfu(u.z) + bb.z)))
            + w.w / (1.f + expf(-(bfu(u.w) + bb.w)));
#pragma unroll
    for (int m = 1; m < 64; m <<= 1) s += __shfl_xor(s, m);
    if (l == 0) al[(size_t)c * BLn + row] = s;
}

// transpose 4 matrices of 256x256 (src[c][d][e] fp32 -> dst[c][e][d] bf16)
__global__ void transpose256(const float* __restrict__ src, bf16* __restrict__ dst)
{
    const float* s = src + (size_t)blockIdx.x * 65536;
    bf16* d = dst + (size_t)blockIdx.x * 65536;
    __shared__ float t[32][33];
    const int tx = threadIdx.x & 31, ty8 = threadIdx.x >> 5;
    for (int bi = 0; bi < 8; ++bi)
        for (int bj = 0; bj < 8; ++bj) {
            __syncthreads();
            for (int r = ty8; r < 32; r += 8)
                t[r][tx] = s[(size_t)(bi * 32 + r) * 256 + bj * 32 + tx];
            __syncthreads();
            for (int r = ty8; r < 32; r += 8)
                stf(&d[(size_t)(bj * 32 + r) * 256 + bi * 32 + tx], t[tx][r]);
        }
}

__global__ void softmax256(const float* __restrict__ in, float* __restrict__ out)
{
    __shared__ float red[256];
    const int row = blockIdx.x, t = threadIdx.x;
    const float v = in[(size_t)row * 256 + t];
    red[t] = v; __syncthreads();
    for (int off = 128; off; off >>= 1) {
        if (t < off) red[t] = fmaxf(red[t], red[t + off]);
        __syncthreads();
    }
    const float mx = red[0]; __syncthreads();
    const float e = expf(v - mx);
    red[t] = e; __syncthreads();
    for (int off = 128; off; off >>= 1) {
        if (t < off) red[t] += red[t + off];
        __syncthreads();
    }
    out[(size_t)row * 256 + t] = e / red[0];
}

// new[c,b,d] = sum_l aa[c,b,l] * x[b,l,d]   (x bf16)
__global__ void weighted_sum_kernel(const float* __restrict__ aa,
                                    const bf16* __restrict__ x,
                                    float* __restrict__ outnew)
{
    const int b = blockIdx.x, c = blockIdx.y, d = threadIdx.x;
    __shared__ float w[Ln];
    w[d] = aa[((size_t)c * Bn + b) * Ln + d];
    __syncthreads();
    float acc = 0.f;
    for (int l = 0; l < Ln; ++l)
        acc += w[l] * ldf(&x[((size_t)b * Ln + l) * Dn + d]);
    outnew[((size_t)c * Bn + b) * Dn + d] = acc;
}

// pack conv filter rows (216) into 256x256 fp32 (rows 216+ zero)
__global__ void wpack_fill(const float* __restrict__ w0, const float* __restrict__ w1,
                           const float* __restrict__ w2, const float* __restrict__ w3,
                           float* __restrict__ wp)
{
    const int f = blockIdx.x;
    if (f < 4) {
        const int cnt[4]  = {4096, 9216, 16384, 25600};
        const int boff[4] = {0, 4096, 13312, 29696};
        const float* src = f == 0 ? w0 : f == 1 ? w1 : f == 2 ? w2 : w3;
        for (int i = threadIdx.x; i < cnt[f]; i += blockDim.x)
            wp[boff[f] + i] = src[i];
    } else {
        for (int i = threadIdx.x; i < 65536 - 55296; i += blockDim.x)
            wp[55296 + i] = 0.f;
    }
}

// nwd[b,row] = dot(new[c_of_row, b, :], wpack[row, :])
__global__ __launch_bounds__(256)
void nwd_kernel(const float* __restrict__ nw, const float* __restrict__ wp,
                float* __restrict__ nwd)
{
    const int b = blockIdx.x;
    __shared__ float ns[4][256];
    for (int i = threadIdx.x; i < 1024; i += 256)
        ns[i >> 8][i & 255] = nw[((size_t)((i >> 8) * Bn + b) << 8) + (i & 255)];
    __syncthreads();
    const int row = threadIdx.x;
    if (row < 216) {
        int f, base;
        if (row < 16)       { f = 0; base = 0; }
        else if (row < 52)  { f = 1; base = 16; }
        else if (row < 116) { f = 2; base = 52; }
        else                { f = 3; base = 116; }
        const int fs = f + 2, local = row - base;
        const int c = (local / fs) & 3;
        const float* wr = wp + (size_t)row * 256;
        float acc = 0.f;
        for (int k = 0; k < 256; ++k) acc += ns[c][k] * wr[k];
        nwd[b * 256 + row] = acc;
    }
}

// conv+relu+maxpool via decomposition over a-weighted x rows + new offset
__global__ __launch_bounds__(256)
void conv_combine(const float* __restrict__ xwT, const float* __restrict__ a,
                  const float* __restrict__ nwd, const float* __restrict__ cb,
                  float* __restrict__ pool, int fs, int base, int poff)
{
    const int b = blockIdx.x, tid = threadIdx.x;
    __shared__ float ash[4][256];
    __shared__ float basev[5];
    __shared__ float red[256];
    for (int i = tid; i < 1024; i += 256)
        ash[i >> 8][i & 255] = a[((size_t)((i >> 8) * Bn + b) << 8) + (i & 255)];
    if (tid < fs) {
        float s = cb[tid];
        for (int c = 0; c < 4; ++c)
            for (int kh = 0; kh < fs; ++kh)
                s += nwd[b * 256 + base + (tid * 4 + c) * fs + kh];
        basev[tid] = s;
    }
    __syncthreads();
    const int ni = Ln - fs + 1;
    const float* xb = xwT + ((size_t)b << 16);
    for (int o = 0; o < fs; ++o) {
        float best = 0.f;
        if (tid < ni) {
            float acc = basev[o];
            for (int c = 0; c < 4; ++c)
                for (int kh = 0; kh < fs; ++kh) {
                    const int row = base + (o * 4 + c) * fs + kh;
                    acc += ash[c][tid + kh] * xb[(row << 8) + tid + kh];
                }
            best = fmaxf(acc, 0.f);
        }
        red[tid] = best; __syncthreads();
        for (int off = 128; off; off >>= 1) {
            if (tid < off) red[tid] = fmaxf(red[tid], red[tid + off]);
            __syncthreads();
        }
        if (tid == 0) pool[b * 14 + poff + o] = red[0];
        __syncthreads();
    }
}

__global__ void fc_kernel(const float* __restrict__ pool, const float* __restrict__ fw,
                          const float* __restrict__ fb, float* __restrict__ out)
{
    const int i = threadIdx.x;           // 256 = B*OUT
    const int b = i >> 1, o = i & 1;
    float acc = fb[o];
#pragma unroll
    for (int f = 0; f < 14; ++f) acc += pool[b * 14 + f] * fw[o * 14 + f];
    out[i] = acc;
}

// ---------------------------------------------------------------------------
extern "C" void kernel_launch(void* const* d_in, const int* in_sizes, int n_in,
                              void* d_out, int out_size, void* d_ws, size_t ws_size,
                              hipStream_t stream)
{
    const int*   utt    = (const int*)  d_in[0];
    const float* emb    = (const float*)d_in[2];
    const float* w_ih0  = (const float*)d_in[3];
    const float* w_hh0  = (const float*)d_in[4];
    const float* b_ih0  = (const float*)d_in[5];
    const float* b_hh0  = (const float*)d_in[6];
    const float* w_ih1  = (const float*)d_in[7];
    const float* w_hh1  = (const float*)d_in[8];
    const float* b_ih1  = (const float*)d_in[9];
    const float* b_hh1  = (const float*)d_in[10];
    const float* att_w  = (const float*)d_in[11];
    const float* att_b  = (const float*)d_in[12];
    const float* att_wv2= (const float*)d_in[13];
    const float* att_bv = (const float*)d_in[14];
    const float* att_wv1= (const float*)d_in[15];
    const float* fc_w   = (const float*)d_in[16];
    const float* fc_b   = (const float*)d_in[17];
    const float* cw[4] = {(const float*)d_in[18], (const float*)d_in[20],
                          (const float*)d_in[22], (const float*)d_in[24]};
    const float* cb[4] = {(const float*)d_in[19], (const float*)d_in[21],
                          (const float*)d_in[23], (const float*)d_in[25]};

    float* ws = (float*)d_ws;
    bf16*  GX   = (bf16*)ws;                          // [0, 12.58M f32)
    bf16*  H1   = (bf16*)(ws + 12582912);             // [12.58M, 16.78M)
    bf16*  H2   = (bf16*)(ws + 16777216);             // [16.78M, 20.97M)
    bf16*  WT   = (bf16*)(ws + 20971520);             //   131,072 f32 slots
    float* WP   = ws + 20971520 + 131072;             //    65,536 f
    float* S    = WP + 65536;                         //   131,072 f
    float* Aa   = S + 131072;
    float* AL   = Aa + 131072;
    float* AAa  = AL + 131072;
    float* NEW_ = AAa + 131072;
    float* NWD  = NEW_ + 131072;                      //    32,768 f
    float* POOL = NWD + 32768;                        //     1,792 f
    // fused-channel MAT/GV buffer: 32768x1024 bf16 = 67MB, exactly fills the
    // dead GX+H1 regions [0, 16.78M f32). XWT (fp32 33.5MB) aliases after.
    bf16*  MATB = (bf16*)ws;
    float* XWT  = ws;

    // layer 0 + scan
    gemm_mfma<float, float, bf16, true, 0><<<dim3(6, 256), 256, 0, stream>>>(
        emb, w_ih0, b_ih0, GX, utt, BLn, 768, En);
    gru_scan_v9<<<dim3(Bn, 2), 768, 0, stream>>>(GX, w_hh0, b_hh0, H1);
    // layer 1 + scan
    gemm_mfma<bf16, float, bf16, false, 0><<<dim3(6, 256), 256, 0, stream>>>(
        H1, w_ih1, b_ih1, GX, nullptr, BLn, 768, Dn);
    gru_scan_v9<<<dim3(Bn, 2), 768, 0, stream>>>(GX, w_hh1, b_hh1, H2);

    // scalar attention: MATB = x @ [att_w^T stacked] (N=1024, one GEMM),
    // then fused 4-channel tanh-sum scores (one launch)
    transpose256<<<4, 256, 0, stream>>>(att_w, WT);
    gemm_mfma<bf16, bf16, bf16, false, 0><<<dim3(8, 256), 256, 0, stream>>>(
        H2, WT, nullptr, MATB, nullptr, BLn, 1024, Dn);
    attn_score_mfma<<<dim3(2, Bn, Cn), 256, 0, stream>>>(H2, MATB, att_b, S);
    softmax256<<<Cn * Bn, 256, 0, stream>>>(S, Aa);

    // vector attention: GVB = x @ [wv2^T stacked] (N=1024), fused reduce
    transpose256<<<4, 256, 0, stream>>>(att_wv2, WT);
    gemm_mfma<bf16, bf16, bf16, false, 0><<<dim3(8, 256), 256, 0, stream>>>(
        H2, WT, nullptr, MATB, nullptr, BLn, 1024, Dn);
    gv_reduce<<<dim3(BLn / 4, Cn), 256, 0, stream>>>(MATB, att_bv, att_wv1, AL);
    softmax256<<<Cn * Bn, 256, 0, stream>>>(AL, AAa);
    weighted_sum_kernel<<<dim3(Bn, Cn), 256, 0, stream>>>(AAa, H2, NEW_);

    // conv stage via xw GEMM decomposition (Cf never materialized)
    wpack_fill<<<5, 256, 0, stream>>>(cw[0], cw[1], cw[2], cw[3], WP);
    gemm_mfma<bf16, float, float, false, 1><<<dim3(2, 256), 256, 0, stream>>>(
        H2, WP, nullptr, XWT, nullptr, BLn, Dn, Dn);
    nwd_kernel<<<Bn, 256, 0, stream>>>(NEW_, WP, NWD);

    const int baserow[4] = {0, 16, 52, 116};
    const int poff[4]    = {0, 2, 5, 9};
    for (int f = 0; f < 4; ++f)
        conv_combine<<<Bn, 256, 0, stream>>>(XWT, Aa, NWD, cb[f], POOL, f + 2, baserow[f], poff[f]);

    fc_kernel<<<1, 256, 0, stream>>>(POOL, fc_w, fc_b, (float*)d_out);
}